// Round 3
// baseline (109.189 us; speedup 1.0000x reference)
//
#include <hip/hip_runtime.h>
#include <math.h>

#define NN 32
#define PI_F 3.14159265358979323846f

// Broadcast lane `lane`'s value of x to all lanes (wave-uniform result -> SGPR).
__device__ __forceinline__ float rl(float x, int lane) {
    return __int_as_float(__builtin_amdgcn_readlane(__float_as_int(x), lane));
}

// Transposed layout: ONE THREAD PER BATCH ELEMENT.
//   - element's psi/r/rd live in the thread's registers (24 dwordx4 loads,
//     contiguous 384 B per thread, 24 KB contiguous per wave, all bytes used)
//   - u_j = r_j sin(psi_j), v_j = r_j cos(psi_j) stay in registers -> NO LDS
//     exchange, NO barriers
//   - wave-invariant A = w_a cos(phi_a), B = w_a sin(phi_a) (zero-diag) are
//     held lane-wise (lane l owns row l) and broadcast per output row i with
//     v_readlane (64 readlane + 128 VALU FMA per i)
//   - psi_dot_i = va2pi_i + c_i P_i - s_i Q_i ; s_i,c_i recomputed from an
//     L2-served psi reload (registers can't be dynamically indexed)
__global__ __launch_bounds__(256, 1)
void hopf_kernel(const float* __restrict__ states,
                 const float* __restrict__ vP,
                 const float* __restrict__ bP,
                 const float* __restrict__ cP,
                 const float* __restrict__ wP,
                 const float* __restrict__ phiP,
                 float* __restrict__ out,
                 const int Btot) {
    const int l = threadIdx.x & 31;   // oscillator row this lane owns

    // ---- phase 0 (per-lane, one-time): activations + A/B row l ----
    const float va2pi = 2.f * PI_F * 5.f / (1.f + __expf(-vP[l]));
    const float ba    = 2.f  / (1.f + __expf(-bP[l]));
    const float ca    = 10.f / (1.f + __expf(-cP[l]));
    // r_d_dot_j = K1_j + K2_j * r_j + K3_j * rd_j
    const float K3 = -ca;
    const float K2 = -ca * ca * 0.25f;
    const float K1 = ca * ca * 0.25f * ba;

    float aA[NN], aB[NN];
#pragma unroll
    for (int j = 0; j < NN; ++j) {
        // zero-diag: flat t=32l+j -> 0 if t%33==0 else param[t/33][t%33-1]
        const int t = 32 * l + j;
        const int a = t / 33;
        const int rem = t - 33 * a;
        const int idx = a * NN + (rem > 0 ? rem - 1 : 0);   // clamped, in-bounds
        const float wv = wP[idx];
        const float pv = phiP[idx];
        const float wa = 1.f / (1.f + __expf(-wv));
        const float pa = 2.f * PI_F / (1.f + __expf(-pv));
        float sp, cp; __sincosf(pa, &sp, &cp);
        aA[j] = (rem != 0) ? wa * cp : 0.f;
        aB[j] = (rem != 0) ? wa * sp : 0.f;
    }

    const int e = blockIdx.x * blockDim.x + threadIdx.x;
    if (e >= Btot) return;

    const float4* s4 = (const float4*)(states + (size_t)e * 96);
    float4* o4 = (float4*)(out + (size_t)e * 96);

    // ---- load element (psi | r | rd), phase A per j: u,v + rdd, store rd/rdd
    float u[NN], v[NN];
#pragma unroll
    for (int k = 0; k < 8; ++k) {
        const float4 ps = s4[k];
        const float4 rr = s4[8 + k];
        const float4 rd = s4[16 + k];
        float4 uu, vv, dd;
        {
            float s, c; __sincosf(ps.x, &s, &c);
            uu.x = rr.x * s; vv.x = rr.x * c;
            dd.x = rl(K1, 4*k+0) + rl(K2, 4*k+0) * rr.x + rl(K3, 4*k+0) * rd.x;
        }
        {
            float s, c; __sincosf(ps.y, &s, &c);
            uu.y = rr.y * s; vv.y = rr.y * c;
            dd.y = rl(K1, 4*k+1) + rl(K2, 4*k+1) * rr.y + rl(K3, 4*k+1) * rd.y;
        }
        {
            float s, c; __sincosf(ps.z, &s, &c);
            uu.z = rr.z * s; vv.z = rr.z * c;
            dd.z = rl(K1, 4*k+2) + rl(K2, 4*k+2) * rr.z + rl(K3, 4*k+2) * rd.z;
        }
        {
            float s, c; __sincosf(ps.w, &s, &c);
            uu.w = rr.w * s; vv.w = rr.w * c;
            dd.w = rl(K1, 4*k+3) + rl(K2, 4*k+3) * rr.w + rl(K3, 4*k+3) * rd.w;
        }
        u[4*k+0] = uu.x; u[4*k+1] = uu.y; u[4*k+2] = uu.z; u[4*k+3] = uu.w;
        v[4*k+0] = vv.x; v[4*k+1] = vv.y; v[4*k+2] = vv.z; v[4*k+3] = vv.w;
        o4[8 + k]  = rd;   // r_d passthrough
        o4[16 + k] = dd;   // r_d_dot
    }

    // ---- phase B: per output row i, P_i/Q_i via readlane-broadcast A/B ----
#pragma unroll 1
    for (int i4 = 0; i4 < 8; ++i4) {
        const float4 psi4 = s4[i4];        // L2/L3-served reload for s_i, c_i
        float4 od;
#pragma unroll
        for (int ii = 0; ii < 4; ++ii) {
            const int i = 4 * i4 + ii;
            float P0 = 0.f, P1 = 0.f, Q0 = 0.f, Q1 = 0.f;
#pragma unroll
            for (int j = 0; j < NN; j += 2) {
                const float a0 = rl(aA[j],     i);
                const float b0 = rl(aB[j],     i);
                const float a1 = rl(aA[j + 1], i);
                const float b1 = rl(aB[j + 1], i);
                P0 = fmaf(a0,  u[j],     P0);
                P0 = fmaf(-b0, v[j],     P0);
                Q0 = fmaf(a0,  v[j],     Q0);
                Q0 = fmaf(b0,  u[j],     Q0);
                P1 = fmaf(a1,  u[j + 1], P1);
                P1 = fmaf(-b1, v[j + 1], P1);
                Q1 = fmaf(a1,  v[j + 1], Q1);
                Q1 = fmaf(b1,  u[j + 1], Q1);
            }
            const float P = P0 + P1;
            const float Q = Q0 + Q1;
            const float psi_i = (ii == 0) ? psi4.x : (ii == 1) ? psi4.y
                              : (ii == 2) ? psi4.z : psi4.w;
            float si, ci; __sincosf(psi_i, &si, &ci);
            const float va = rl(va2pi, i);
            ((float*)&od)[ii] = fmaf(ci, P, fmaf(-si, Q, va));
        }
        o4[i4] = od;   // psi_dot
    }
}

extern "C" void kernel_launch(void* const* d_in, const int* in_sizes, int n_in,
                              void* d_out, int out_size, void* d_ws, size_t ws_size,
                              hipStream_t stream) {
    const float* states = (const float*)d_in[0];
    const float* v      = (const float*)d_in[1];
    const float* b      = (const float*)d_in[2];
    const float* c      = (const float*)d_in[3];
    const float* w      = (const float*)d_in[4];
    const float* phi    = (const float*)d_in[5];
    float* out = (float*)d_out;

    const int B = in_sizes[0] / 96;          // 65536
    const int blocks = (B + 255) / 256;      // 256 blocks -> 1 block/CU, 1 wave/SIMD

    hopf_kernel<<<blocks, 256, 0, stream>>>(states, v, b, c, w, phi, out, B);
}